// Round 9
// baseline (277.680 us; speedup 1.0000x reference)
//
#include <hip/hip_runtime.h>

// Problem constants
#define NN   768
#define KKN  32
#define CS   384
#define CZ   128
#define CG   16
#define NH   4
#define DHD  32
#define NRBF 64
#define EE   (NN*KKN)

#define RBF_STEP    (20.0f/63.0f)
#define RBF_INVSTEP (63.0f/20.0f)
#define RBF_INVSIG  3.2f            // 1/0.3125
#define RBF_SI      (RBF_STEP*RBF_INVSIG)

typedef __attribute__((ext_vector_type(8))) short bf16x8;
typedef __attribute__((ext_vector_type(4))) float f32x4;

// ---------- helpers ----------
__device__ __forceinline__ unsigned short f2bf(float f){
  unsigned int u = __float_as_uint(f);
  u += 0x7FFFu + ((u >> 16) & 1u);
  return (unsigned short)(u >> 16);
}
__device__ __forceinline__ float bfl(unsigned int u){ return __uint_as_float(u << 16); }
__device__ __forceinline__ float bfh(unsigned int u){ return __uint_as_float(u & 0xFFFF0000u); }
// RNE bf16 pair pack: 2x(bfe+add3) + v_perm_b32
__device__ __forceinline__ unsigned int packbf(float a, float b){
  unsigned int ua = __float_as_uint(a), ub = __float_as_uint(b);
  ua = ua + 0x7FFFu + ((ua >> 16) & 1u);
  ub = ub + 0x7FFFu + ((ub >> 16) & 1u);
  return __builtin_amdgcn_perm(ub, ua, 0x07060302u);  // bytes: [ub3 ub2 ua3 ua2]
}
__device__ __forceinline__ float sigm(float x){ return 1.0f/(1.0f + __expf(-x)); }

// ---------- K0: one-time weight transpose/pack into ws + nl/nr zero-init ----------
__global__ __launch_bounds__(256) void k0_prep(
    const float* __restrict__ wq, const float* __restrict__ wkv,
    const float* __restrict__ wog, const float* __restrict__ wout,
    const float* __restrict__ wd, const float* __restrict__ wt,
    const float* __restrict__ wb,
    unsigned short* __restrict__ wqkvogT, unsigned short* __restrict__ woutT,
    unsigned short* __restrict__ wdT, unsigned short* __restrict__ wtT,
    unsigned short* __restrict__ wbP, float* __restrict__ nlzero)
{
  int id = blockIdx.x*256 + threadIdx.x;
  float v[8];
  if (id < 8192){
    int c = id & 511, g = id >> 9;
    const float* src; int ld, col;
    if (c < 128){ src = wq; ld = 128; col = c; }
    else if (c < 384){ src = wkv; ld = 256; col = c-128; }
    else { src = wog; ld = 128; col = c-384; }
    #pragma unroll
    for (int j=0;j<8;j++) v[j] = src[(size_t)(g*8+j)*ld + col];
    *(uint4*)(wqkvogT + c*128 + ((g + c)&15)*8) = make_uint4(
      packbf(v[0],v[1]),packbf(v[2],v[3]),packbf(v[4],v[5]),packbf(v[6],v[7]));
  } else if (id < 10240){
    int l = id - 8192; int c = l & 127, g = l >> 7;
    #pragma unroll
    for (int j=0;j<8;j++) v[j] = wout[(size_t)(g*8+j)*128 + c];
    *(uint4*)(woutT + c*128 + ((g + c)&15)*8) = make_uint4(
      packbf(v[0],v[1]),packbf(v[2],v[3]),packbf(v[4],v[5]),packbf(v[6],v[7]));
  } else if (id < 11392){
    int l = id - 10240; int c = l & 127, g = l >> 7;   // g 0..8
    #pragma unroll
    for (int j=0;j<8;j++) v[j] = (g<8) ? wd[(size_t)(g*8+j)*128 + c] : 0.f;
    *(uint4*)(wdT + c*72 + g*8) = make_uint4(
      packbf(v[0],v[1]),packbf(v[2],v[3]),packbf(v[4],v[5]),packbf(v[6],v[7]));
  } else if (id < 11460){
    int l = id - 11392; int h = l / 17, g = l % 17;
    #pragma unroll
    for (int j=0;j<8;j++){ int cc = g*8+j; v[j] = (cc<128)? wt[cc*4 + h] : 0.f; }
    *(uint4*)(wtT + h*136 + g*8) = make_uint4(
      packbf(v[0],v[1]),packbf(v[2],v[3]),packbf(v[4],v[5]),packbf(v[6],v[7]));
  } else if (id < 15556){
    int l2 = id - 11460;           // 0..4095
    int c = l2 >> 5, sl = l2 & 31; // c 0..127, sl 0..31
    int kl0 = sl*8;
    #pragma unroll
    for (int j=0;j<8;j++) v[j] = wb[(size_t)(kl0+j)*128 + c];
    *(uint4*)(wbP + c*256 + kl0) = make_uint4(
      packbf(v[0],v[1]),packbf(v[2],v[3]),packbf(v[4],v[5]),packbf(v[6],v[7]));
  } else if (id < 21700){
    int z = id - 15556;            // 0..6143 -> zero nlw+nrw (24576 floats)
    ((float4*)nlzero)[z] = make_float4(0.f,0.f,0.f,0.f);
  }
}

// ---------- K1: nl/nr (K-split x4, atomics) + LayerNorm -> bf16 z ----------
__global__ __launch_bounds__(256) void k1_pre(
    const float* __restrict__ nf, const float* __restrict__ ef,
    const float* __restrict__ wl, const float* __restrict__ bl,
    const float* __restrict__ wr, const float* __restrict__ br,
    const float* __restrict__ lng, const float* __restrict__ lnb,
    float* __restrict__ nlw, float* __restrict__ nrw,
    unsigned short* __restrict__ zw)
{
  int b = blockIdx.x, t = threadIdx.x;
  if (b < 1536){
    int rl = t >> 4, l16 = t & 15;
    size_t e = (size_t)b*16 + rl;
    const float4* row = (const float4*)(ef + e*CZ);
    float4 x0 = row[l16*2], x1 = row[l16*2+1];
    float v[8] = {x0.x,x0.y,x0.z,x0.w,x1.x,x1.y,x1.z,x1.w};
    float s = 0.f, q = 0.f;
    #pragma unroll
    for (int u=0;u<8;u++){ s += v[u]; q += v[u]*v[u]; }
    #pragma unroll
    for (int m=1;m<16;m<<=1){ s += __shfl_xor(s,m); q += __shfl_xor(q,m); }
    float mean = s*(1.f/128.f);
    float var  = q*(1.f/128.f) - mean*mean;
    float rs = rsqrtf(var + 1e-5f);
    int c0 = l16*8;
    unsigned int pk[4];
    #pragma unroll
    for (int u=0;u<4;u++){
      float z0 = (v[2*u]  -mean)*rs*lng[c0+2*u]   + lnb[c0+2*u];
      float z1 = (v[2*u+1]-mean)*rs*lng[c0+2*u+1] + lnb[c0+2*u+1];
      pk[u] = packbf(z0,z1);
    }
    ((uint4*)(zw + e*CZ))[l16] = make_uint4(pk[0],pk[1],pk[2],pk[3]);
  } else {
    int blk2 = b - 1536;           // 0..383
    int seg = blk2 / 96;           // 0..3
    int within = blk2 - seg*96;
    int gid = within*256 + t;      // 0..24575
    int side = (gid >= 12288) ? 1 : 0;
    int idx = gid - side*12288;
    int nd = idx >> 4, c = idx & 15;
    const float* w = side ? wr : wl;
    float acc = (seg==0) ? (side ? br[c] : bl[c]) : 0.f;
    const float* nrow = nf + (size_t)nd*CS;
    int kb = seg*96;
    #pragma unroll 4
    for (int k=kb;k<kb+96;k++) acc += nrow[k]*w[k*CG+c];
    atomicAdd((side? nrw : nlw)+idx, acc);
  }
}

// ---------- K1b: S_all[s][c*16+l] = nl[s] . wb   (768 blocks) + nr bf16 pack ----------
__global__ __launch_bounds__(256) void k1b_sprep(
    const float* __restrict__ nlw, const float* __restrict__ nrw,
    const unsigned short* __restrict__ wbP,
    unsigned short* __restrict__ S_all, unsigned short* __restrict__ nrb)
{
  int n = blockIdx.x, t = threadIdx.x;
  float e1[16];
  #pragma unroll
  for (int k=0;k<16;k++) e1[k] = nlw[n*CG + k];
  int c = t>>1, l0 = (t&1)*8;
  float S[8];
  #pragma unroll
  for (int u=0;u<8;u++) S[u]=0.f;
  const unsigned short* wrow = wbP + c*256 + l0;
  #pragma unroll 4
  for (int k=0;k<16;k++){
    uint4 wv = *(const uint4*)(wrow + k*16);
    float wf[8] = { bfl(wv.x), bfh(wv.x), bfl(wv.y), bfh(wv.y),
                    bfl(wv.z), bfh(wv.z), bfl(wv.w), bfh(wv.w) };
    float ev = e1[k];
    #pragma unroll
    for (int u=0;u<8;u++) S[u] += ev*wf[u];
  }
  *(uint4*)(S_all + (size_t)n*2048 + c*16 + l0) = make_uint4(
    packbf(S[0],S[1]), packbf(S[2],S[3]), packbf(S[4],S[5]), packbf(S[6],S[7]));
  if (t < 8){
    *(unsigned int*)(nrb + n*CG + 2*t) = packbf(nrw[n*CG + 2*t], nrw[n*CG + 2*t + 1]);
  }
}

// ---------- K2 (MFMA, lean+pipelined): bias[n][h][i][j] per (node, 4-i chunk) ----------
__global__ __launch_bounds__(256,5) void k2_bias(
    const long long* __restrict__ eidx, const float* __restrict__ trans,
    const unsigned short* __restrict__ S_all, const unsigned short* __restrict__ nrb,
    const unsigned short* __restrict__ wdTg, const unsigned short* __restrict__ wtTg,
    const float* __restrict__ bg, const float* __restrict__ bd,
    float* __restrict__ biasw)
{
  int n = blockIdx.x >> 3, chunk = blockIdx.x & 7;
  int i0 = chunk*4;
  int t = threadIdx.x;
  int wave = t>>6, lane = t&63, q = lane>>4, l15 = lane&15;

  __shared__ __align__(16) unsigned short rbfb[32*72];   // 4.5 KB  [j][r]
  __shared__ __align__(16) unsigned short Xb  [32*136];  // 8.5 KB  [j][c]
  __shared__ __align__(16) float t3s[32][4];
  __shared__ __align__(16) float dsm[4][32];
  __shared__ int srcs[32];

  f32x4 zero4 = {0.f,0.f,0.f,0.f};
  uint4 uz = make_uint4(0,0,0,0);

  // ph0: srcs
  if (t < 32) srcs[t] = (int)eidx[(size_t)n*KKN + t];
  __syncthreads();
  // ph1: t3s gather + per-lane invariant fragments (wd, wt, e2, bg/bd, aS(i0))
  if (t < 32){ int s = srcs[t];
    t3s[t][0]=trans[s*3]; t3s[t][1]=trans[s*3+1]; t3s[t][2]=trans[s*3+2]; }
  uint4 wdf[2][2];
  #pragma unroll
  for (int mt=0;mt<2;mt++){
    #pragma unroll
    for (int ks=0;ks<2;ks++)
      wdf[mt][ks] = *(const uint4*)(wdTg + (wave*32+mt*16+l15)*72 + ks*32 + q*8);
  }
  uint4 wtf[4];
  #pragma unroll
  for (int ks=0;ks<4;ks++)
    wtf[ks] = *(const uint4*)(wtTg + (l15&3)*136 + ks*32 + q*8);
  uint4 bE[2];
  #pragma unroll
  for (int nt=0;nt<2;nt++){
    int jn = srcs[nt*16 + l15];
    bE[nt] = (q < 2) ? *(const uint4*)(nrb + jn*CG + q*8) : uz;
  }
  float4 bgv2[2], bdv2[2];
  #pragma unroll
  for (int mt=0;mt<2;mt++){
    int c0 = wave*32 + mt*16 + q*4;
    bgv2[mt] = *(const float4*)(bg + c0);
    bdv2[mt] = *(const float4*)(bd + c0);
  }
  uint4 aSc[2], aSn[2];
  {
    int s0 = srcs[i0];
    #pragma unroll
    for (int mt=0;mt<2;mt++)
      aSc[mt] = (q < 2) ? *(const uint4*)(S_all + (size_t)s0*2048 + (wave*32+mt*16+l15)*16 + q*8) : uz;
  }
  __syncthreads();
  // ph2: distances
  if (t < 128){
    int ii=t>>5, j=t&31;
    float dx=t3s[i0+ii][0]-t3s[j][0]+1e-8f;
    float dy=t3s[i0+ii][1]-t3s[j][1]+1e-8f;
    float dz=t3s[i0+ii][2]-t3s[j][2]+1e-8f;
    dsm[ii][j]=sqrtf(dx*dx+dy*dy+dz*dz);
  }
  __syncthreads();

  int jr = t>>3, sl = t&7;

  #pragma unroll 1
  for (int ii=0; ii<4; ii++){
    // prefetch next i's aS (consumed next iteration; full iteration to cover latency)
    if (ii < 3){
      int s_n = srcs[i0+ii+1];
      #pragma unroll
      for (int mt=0;mt<2;mt++)
        aSn[mt] = (q < 2) ? *(const uint4*)(S_all + (size_t)s_n*2048 + (wave*32+mt*16+l15)*16 + q*8) : uz;
    }
    // dense rbf fill (out-of-range terms underflow to exact 0)
    {
      float dI = dsm[ii][jr]*RBF_INVSIG;
      #pragma unroll
      for (int u=0;u<9;u++){
        int r = sl*9+u;
        float x = fmaf((float)r, -RBF_SI, dI);
        rbfb[jr*72+r] = f2bf(__expf(-x*x));
      }
    }
    __syncthreads();

    f32x4 ga[2][2], da[2][2];
    #pragma unroll
    for(int a=0;a<2;a++){
      #pragma unroll
      for(int b2=0;b2<2;b2++){ ga[a][b2]=zero4; da[a][b2]=zero4; }
    }
    #pragma unroll
    for(int mt=0;mt<2;mt++){
      #pragma unroll
      for(int nt=0;nt<2;nt++)
        ga[mt][nt] = __builtin_amdgcn_mfma_f32_16x16x32_bf16(
          *(const bf16x8*)&aSc[mt], *(const bf16x8*)&bE[nt], ga[mt][nt], 0,0,0);
    }
    #pragma unroll
    for(int ks=0;ks<2;ks++){
      bf16x8 bR[2];
      #pragma unroll
      for(int nt=0;nt<2;nt++) bR[nt] = *(const bf16x8*)&rbfb[(nt*16+l15)*72 + ks*32 + q*8];
      #pragma unroll
      for(int mt=0;mt<2;mt++){
        #pragma unroll
        for(int nt=0;nt<2;nt++)
          da[mt][nt] = __builtin_amdgcn_mfma_f32_16x16x32_bf16(
            *(const bf16x8*)&wdf[mt][ks], bR[nt], da[mt][nt], 0,0,0);
      }
    }
    // epilogue: X[j][c] = sigmoid(ga+bg)*(da+bd), bf16
    #pragma unroll
    for(int mt=0;mt<2;mt++){
      int c0 = wave*32 + mt*16 + q*4;
      float4 bgv = bgv2[mt];
      float4 bdv = bdv2[mt];
      #pragma unroll
      for(int nt=0;nt<2;nt++){
        float x0 = sigm(ga[mt][nt][0]+bgv.x)*(da[mt][nt][0]+bdv.x);
        float x1 = sigm(ga[mt][nt][1]+bgv.y)*(da[mt][nt][1]+bdv.y);
        float x2 = sigm(ga[mt][nt][2]+bgv.z)*(da[mt][nt][2]+bdv.z);
        float x3 = sigm(ga[mt][nt][3]+bgv.w)*(da[mt][nt][3]+bdv.w);
        *(uint2*)&Xb[(nt*16+l15)*136 + c0] = make_uint2(packbf(x0,x1), packbf(x2,x3));
      }
    }
    __syncthreads();

    // final: biasT[h][j] = wt[h][:] . X[j][:], waves 0,1 (j-halves)
    if (wave < 2){
      f32x4 bacc = {0.f,0.f,0.f,0.f};
      #pragma unroll
      for(int ks=0;ks<4;ks++){
        bf16x8 bX = *(const bf16x8*)&Xb[(wave*16+l15)*136 + ks*32 + q*8];
        bacc = __builtin_amdgcn_mfma_f32_16x16x32_bf16(*(const bf16x8*)&wtf[ks], bX, bacc, 0,0,0);
      }
      if (q==0){   // rows h=0..3 in quad-0 regs; layout [n][h][i][j]
        int j = wave*16 + l15;
        float* base = biasw + (((size_t)n*4)*32 + (i0+ii))*32 + j;
        base[0] = bacc[0]; base[1024] = bacc[1]; base[2048] = bacc[2]; base[3072] = bacc[3];
      }
    }
    aSc[0] = aSn[0]; aSc[1] = aSn[1];
  }
}

// ---------- K3: per-node QKV+og (MFMA) + attention + out-proj (MFMA) ----------
__global__ __launch_bounds__(256,3) void k3_attn(
    const unsigned short* __restrict__ zw, const float* __restrict__ biasw,
    const unsigned short* __restrict__ wqkvogT, const unsigned short* __restrict__ woutT,
    const float* __restrict__ bq, const float* __restrict__ bkv, const float* __restrict__ bog,
    const float* __restrict__ bout, float* __restrict__ out)
{
  int n = blockIdx.x, t = threadIdx.x;
  int w = t>>6, lane = t&63, q = lane>>4, l15 = lane&15;
  int i3 = lane>>1, jh = lane&1;

  __shared__ __align__(16) char smem[49152];
  uint4* wdst = (uint4*)(smem + 32768);
  unsigned short* wtS = (unsigned short*)(smem + 32768);
  f32x4 zero4 = {0.f,0.f,0.f,0.f};

  bf16x8 zfr[2][4];
  #pragma unroll
  for (int nt=0;nt<2;nt++){
    const unsigned short* zr = zw + ((size_t)n*32 + nt*16 + l15)*128;
    #pragma unroll
    for (int ks=0;ks<4;ks++) zfr[nt][ks] = *(const bf16x8*)(zr + ks*32 + q*8);
  }
  f32x4 br4[4];
  {
    const f32x4* bsrc = (const f32x4*)(biasw + (((size_t)n*4 + w)*32 + i3)*32 + jh*16);
    #pragma unroll
    for (int u=0;u<4;u++) br4[u] = bsrc[u];
  }
  const float* bseg = (w==0)? bq : (w==1)? bkv : (w==2)? (bkv+128) : bog;

  const uint4* wsrc = (const uint4*)wqkvogT;
  int sb = w*2048, db = w*256;
  uint4 sreg[4];
  #pragma unroll
  for (int u=0;u<4;u++) sreg[u] = wsrc[sb + u*64 + lane];
  const unsigned short* arow = wtS + w*2048 + l15*128;
  for (int r=0;r<8;r++){
    #pragma unroll
    for (int u=0;u<4;u++) wdst[db + u*64 + lane] = sreg[u];
    if (r<7){
      #pragma unroll
      for (int u=0;u<4;u++) sreg[u] = wsrc[sb + (r+1)*256 + u*64 + lane];
    }
    float4 bv = *(const float4*)(bseg + r*16 + q*4);
    f32x4 acc0 = zero4, acc1 = zero4;
    int cg = w*128 + r*16 + l15;
    #pragma unroll
    for (int ks=0;ks<4;ks++){
      bf16x8 af = *(const bf16x8*)(arow + (((ks*4+q) + cg)&15)*8);
      acc0 = __builtin_amdgcn_mfma_f32_16x16x32_bf16(af, zfr[0][ks], acc0, 0,0,0);
      acc1 = __builtin_amdgcn_mfma_f32_16x16x32_bf16(af, zfr[1][ks], acc1, 0,0,0);
    }
    #pragma unroll
    for (int nt=0;nt<2;nt++){
      f32x4 a = nt? acc1 : acc0;
      float v0,v1,v2,v3;
      if (w==3){ v0=sigm(a[0]+bv.x); v1=sigm(a[1]+bv.y); v2=sigm(a[2]+bv.z); v3=sigm(a[3]+bv.w); }
      else     { v0=a[0]+bv.x; v1=a[1]+bv.y; v2=a[2]+bv.z; v3=a[3]+bv.w; }
      int i = nt*16 + l15;
      int blk = ((r*2 + (q>>1)) + i) & 15;
      *(uint2*)(smem + w*8192 + i*256 + blk*16 + (q&1)*8) = make_uint2(packbf(v0,v1), packbf(v2,v3));
    }
  }
  __syncthreads();

  float sc[16];
  {
    float qreg[32];
    #pragma unroll
    for (int dq=0;dq<4;dq++){
      uint4 qa = *(const uint4*)(smem + i3*256 + (((w*4+dq) + i3)&15)*16);
      unsigned int qu[4] = {qa.x,qa.y,qa.z,qa.w};
      #pragma unroll
      for (int u2=0;u2<4;u2++){ qreg[dq*8+2*u2]=bfl(qu[u2]); qreg[dq*8+2*u2+1]=bfh(qu[u2]); }
    }
    int j0 = jh*16;
    #pragma unroll
    for (int jj=0;jj<16;jj++){
      int j = j0+jj;
      float s = 0.f;
      #pragma unroll
      for (int dq=0;dq<4;dq++){
        uint4 ka = *(const uint4*)(smem + 8192 + j*256 + (((w*4+dq) + j)&15)*16);
        unsigned int ku[4] = {ka.x,ka.y,ka.z,ka.w};
        #pragma unroll
        for (int u2=0;u2<4;u2++)
          s += qreg[dq*8+2*u2]*bfl(ku[u2]) + qreg[dq*8+2*u2+1]*bfh(ku[u2]);
      }
      sc[jj] = s*0.17677669529663687f + br4[jj>>2][jj&3];
    }
  }
  {
    float mx = sc[0];
    #pragma unroll
    for (int jj=1;jj<16;jj++) mx = fmaxf(mx, sc[jj]);
    mx = fmaxf(mx, __shfl_xor(mx,1));
    float sum = 0.f;
    #pragma unroll
    for (int jj=0;jj<16;jj++){ sc[jj] = __expf(sc[jj]-mx); sum += sc[jj]; }
    sum += __shfl_xor(sum,1);
    float inv = 1.0f/sum;
    #pragma unroll
    for (int jj=0;jj<16;jj++) sc[jj] *= inv;
  }
  __syncthreads();
  {
    int dbase = w*32 + jh*16;
    int db8 = dbase >> 3;
    float o16[16];
    #pragma unroll
    for (int u=0;u<16;u++) o16[u]=0.f;
    #pragma unroll
    for (int j=0;j<32;j++){
      float pj = __shfl(sc[j & 15], (lane & 62) | (j >> 4));
      uint4 va0 = *(const uint4*)(smem + 16384 + j*256 + (((db8+0) + j)&15)*16);
      uint4 va1 = *(const uint4*)(smem + 16384 + j*256 + (((db8+1) + j)&15)*16);
      unsigned int vu[8] = {va0.x,va0.y,va0.z,va0.w,va1.x,va1.y,va1.z,va1.w};
      #pragma unroll
      for (int u2=0;u2<8;u2++){ o16[2*u2] += pj*bfl(vu[u2]); o16[2*u2+1] += pj*bfh(vu[u2]); }
    }
    uint4 ga0 = *(const uint4*)(smem + 24576 + i3*256 + (((db8+0) + i3)&15)*16);
    uint4 ga1 = *(const uint4*)(smem + 24576 + i3*256 + (((db8+1) + i3)&15)*16);
    unsigned int gu[8] = {ga0.x,ga0.y,ga0.z,ga0.w,ga1.x,ga1.y,ga1.z,ga1.w};
    #pragma unroll
    for (int u2=0;u2<8;u2++){
      float y0 = o16[2*u2]  *bfl(gu[u2]);
      float y1 = o16[2*u2+1]*bfh(gu[u2]);
      int c = dbase + 2*u2;
      *(unsigned int*)(smem + i3*256 + (((c>>3) + i3)&15)*16 + (c&7)*2) = packbf(y0,y1);
    }
  }
  __syncthreads();

  bf16x8 yfr[2][4];
  #pragma unroll
  for (int mt=0;mt<2;mt++){
    int row = mt*16 + l15;
    #pragma unroll
    for (int ks=0;ks<4;ks++)
      yfr[mt][ks] = *(const bf16x8*)(smem + row*256 + (((ks*4+q) + row)&15)*16);
  }
  const uint4* osrc = (const uint4*)woutT;
  #pragma unroll
  for (int r2=0;r2<2;r2++){
    int c0 = (r2*4 + w)*16;
    #pragma unroll
    for (int u=0;u<4;u++) wdst[db + u*64 + lane] = osrc[c0*16 + u*64 + lane];
    int cg2 = c0 + l15;
    const unsigned short* brow = wtS + w*2048 + l15*128;
    f32x4 oa0 = zero4, oa1 = zero4;
    #pragma unroll
    for (int ks=0;ks<4;ks++){
      bf16x8 bf = *(const bf16x8*)(brow + (((ks*4+q) + cg2)&15)*8);
      oa0 = __builtin_amdgcn_mfma_f32_16x16x32_bf16(yfr[0][ks], bf, oa0, 0,0,0);
      oa1 = __builtin_amdgcn_mfma_f32_16x16x32_bf16(yfr[1][ks], bf, oa1, 0,0,0);
    }
    float bov = bout[cg2];
    #pragma unroll
    for (int mt=0;mt<2;mt++){
      f32x4 oa = mt? oa1 : oa0;
      #pragma unroll
      for (int rg=0; rg<4; rg++){
        int i = mt*16 + q*4 + rg;
        out[((size_t)n*32 + i)*128 + cg2] = oa[rg] + bov;
      }
    }
  }
}

// ---------- launch ----------
extern "C" void kernel_launch(void* const* d_in, const int* in_sizes, int n_in,
                              void* d_out, int out_size, void* d_ws, size_t ws_size,
                              hipStream_t stream)
{
  const float* nf  = (const float*)d_in[0];
  const float* tr  = (const float*)d_in[1];
  const float* ef  = (const float*)d_in[2];
  const long long* ei = (const long long*)d_in[3];
  const float* wl  = (const float*)d_in[4];  const float* bl  = (const float*)d_in[5];
  const float* wr  = (const float*)d_in[6];  const float* br  = (const float*)d_in[7];
  const float* wbg = (const float*)d_in[8];  const float* bbg = (const float*)d_in[9];
  const float* wdi = (const float*)d_in[10]; const float* bdi = (const float*)d_in[11];
  const float* wtb = (const float*)d_in[12];
  const float* lng = (const float*)d_in[13]; const float* lnb = (const float*)d_in[14];
  const float* wq  = (const float*)d_in[15]; const float* bq  = (const float*)d_in[16];
  const float* wkv = (const float*)d_in[17]; const float* bkv = (const float*)d_in[18];
  const float* wo  = (const float*)d_in[19]; const float* bo  = (const float*)d_in[20];
  const float* wog = (const float*)d_in[21]; const float* bog = (const float*)d_in[22];
  float* outp = (float*)d_out;
  float* ws = (float*)d_ws;
  // ws layout (floats). zw = E*CZ bf16 = 1,572,864 floats.
  float* nlw = ws;                                            // [0, 12288)
  float* nrw = ws + 12288;                                    // [12288, 24576)
  float* biasw = ws + 24576;                                  // [24576, 3170304)  [n][h][i][j]
  unsigned short* zw      = (unsigned short*)(ws + 3170304);  // [3170304, 4743168)
  unsigned short* wqkvogT = (unsigned short*)(ws + 4743168);  // 32768 floats
  unsigned short* woutT   = (unsigned short*)(ws + 4775936);  // 8192 floats
  unsigned short* wdTg    = (unsigned short*)(ws + 4784128);  // 4608 floats
  unsigned short* wtTg    = (unsigned short*)(ws + 4788736);  // 1088 floats
  unsigned short* wbPg    = (unsigned short*)(ws + 4789824);  // 16384 floats
  unsigned short* S_all   = (unsigned short*)(ws + 4806208);  // 786432 floats
  unsigned short* nrb     = (unsigned short*)(ws + 5592640);  // 6144 floats -> end 5598784

  hipLaunchKernelGGL(k0_prep, dim3(85), dim3(256), 0, stream,
                     wq, wkv, wog, wo, wdi, wtb, wbg, wqkvogT, woutT, wdTg, wtTg, wbPg, nlw);
  hipLaunchKernelGGL(k1_pre, dim3(1920), dim3(256), 0, stream,
                     nf, ef, wl, bl, wr, br, lng, lnb, nlw, nrw, zw);
  hipLaunchKernelGGL(k1b_sprep, dim3(768), dim3(256), 0, stream,
                     nlw, nrw, wbPg, S_all, nrb);
  hipLaunchKernelGGL(k2_bias, dim3(6144), dim3(256), 0, stream,
                     ei, tr, S_all, nrb, wdTg, wtTg, bbg, bdi, biasw);
  hipLaunchKernelGGL(k3_attn, dim3(768), dim3(256), 0, stream,
                     zw, biasw, wqkvogT, woutT, bq, bkv, bog, bo, outp);
}

// Round 10
// 256.333 us; speedup vs baseline: 1.0833x; 1.0833x over previous
//
#include <hip/hip_runtime.h>

// Problem constants
#define NN   768
#define KKN  32
#define CS   384
#define CZ   128
#define CG   16
#define NH   4
#define DHD  32
#define NRBF 64
#define EE   (NN*KKN)

#define RBF_STEP    (20.0f/63.0f)
#define RBF_INVSTEP (63.0f/20.0f)
#define RBF_INVSIG  3.2f            // 1/0.3125
#define RBF_SI      (RBF_STEP*RBF_INVSIG)

typedef __attribute__((ext_vector_type(8))) short bf16x8;
typedef __attribute__((ext_vector_type(4))) float f32x4;

// ---------- helpers ----------
__device__ __forceinline__ unsigned short f2bf(float f){
  unsigned int u = __float_as_uint(f);
  u += 0x7FFFu + ((u >> 16) & 1u);
  return (unsigned short)(u >> 16);
}
__device__ __forceinline__ float bfl(unsigned int u){ return __uint_as_float(u << 16); }
__device__ __forceinline__ float bfh(unsigned int u){ return __uint_as_float(u & 0xFFFF0000u); }
// RNE bf16 pair pack: 2x(bfe+add3) + v_perm_b32
__device__ __forceinline__ unsigned int packbf(float a, float b){
  unsigned int ua = __float_as_uint(a), ub = __float_as_uint(b);
  ua = ua + 0x7FFFu + ((ua >> 16) & 1u);
  ub = ub + 0x7FFFu + ((ub >> 16) & 1u);
  return __builtin_amdgcn_perm(ub, ua, 0x07060302u);  // bytes: [ub3 ub2 ua3 ua2]
}
__device__ __forceinline__ float sigm(float x){ return 1.0f/(1.0f + __expf(-x)); }

// ---------- K0: one-time weight transpose/pack into ws + nl/nr zero-init ----------
__global__ __launch_bounds__(256) void k0_prep(
    const float* __restrict__ wq, const float* __restrict__ wkv,
    const float* __restrict__ wog, const float* __restrict__ wout,
    const float* __restrict__ wd, const float* __restrict__ wt,
    const float* __restrict__ wb,
    unsigned short* __restrict__ wqkvogT, unsigned short* __restrict__ woutT,
    unsigned short* __restrict__ wdT, unsigned short* __restrict__ wtT,
    unsigned short* __restrict__ wbP, float* __restrict__ nlzero)
{
  int id = blockIdx.x*256 + threadIdx.x;
  float v[8];
  if (id < 8192){
    int c = id & 511, g = id >> 9;
    const float* src; int ld, col;
    if (c < 128){ src = wq; ld = 128; col = c; }
    else if (c < 384){ src = wkv; ld = 256; col = c-128; }
    else { src = wog; ld = 128; col = c-384; }
    #pragma unroll
    for (int j=0;j<8;j++) v[j] = src[(size_t)(g*8+j)*ld + col];
    *(uint4*)(wqkvogT + c*128 + ((g + c)&15)*8) = make_uint4(
      packbf(v[0],v[1]),packbf(v[2],v[3]),packbf(v[4],v[5]),packbf(v[6],v[7]));
  } else if (id < 10240){
    int l = id - 8192; int c = l & 127, g = l >> 7;
    #pragma unroll
    for (int j=0;j<8;j++) v[j] = wout[(size_t)(g*8+j)*128 + c];
    *(uint4*)(woutT + c*128 + ((g + c)&15)*8) = make_uint4(
      packbf(v[0],v[1]),packbf(v[2],v[3]),packbf(v[4],v[5]),packbf(v[6],v[7]));
  } else if (id < 11392){
    int l = id - 10240; int c = l & 127, g = l >> 7;   // g 0..8
    #pragma unroll
    for (int j=0;j<8;j++) v[j] = (g<8) ? wd[(size_t)(g*8+j)*128 + c] : 0.f;
    *(uint4*)(wdT + c*72 + g*8) = make_uint4(
      packbf(v[0],v[1]),packbf(v[2],v[3]),packbf(v[4],v[5]),packbf(v[6],v[7]));
  } else if (id < 11460){
    int l = id - 11392; int h = l / 17, g = l % 17;
    #pragma unroll
    for (int j=0;j<8;j++){ int cc = g*8+j; v[j] = (cc<128)? wt[cc*4 + h] : 0.f; }
    *(uint4*)(wtT + h*136 + g*8) = make_uint4(
      packbf(v[0],v[1]),packbf(v[2],v[3]),packbf(v[4],v[5]),packbf(v[6],v[7]));
  } else if (id < 15556){
    int l2 = id - 11460;           // 0..4095
    int c = l2 >> 5, sl = l2 & 31; // c 0..127, sl 0..31
    int kl0 = sl*8;
    #pragma unroll
    for (int j=0;j<8;j++) v[j] = wb[(size_t)(kl0+j)*128 + c];
    *(uint4*)(wbP + c*256 + kl0) = make_uint4(
      packbf(v[0],v[1]),packbf(v[2],v[3]),packbf(v[4],v[5]),packbf(v[6],v[7]));
  } else if (id < 21700){
    int z = id - 15556;            // 0..6143 -> zero nlw+nrw (24576 floats)
    ((float4*)nlzero)[z] = make_float4(0.f,0.f,0.f,0.f);
  }
}

// ---------- K1: nl/nr (K-split x4, atomics) + LayerNorm -> bf16 z ----------
__global__ __launch_bounds__(256) void k1_pre(
    const float* __restrict__ nf, const float* __restrict__ ef,
    const float* __restrict__ wl, const float* __restrict__ bl,
    const float* __restrict__ wr, const float* __restrict__ br,
    const float* __restrict__ lng, const float* __restrict__ lnb,
    float* __restrict__ nlw, float* __restrict__ nrw,
    unsigned short* __restrict__ zw)
{
  int b = blockIdx.x, t = threadIdx.x;
  if (b < 1536){
    int rl = t >> 4, l16 = t & 15;
    size_t e = (size_t)b*16 + rl;
    const float4* row = (const float4*)(ef + e*CZ);
    float4 x0 = row[l16*2], x1 = row[l16*2+1];
    float v[8] = {x0.x,x0.y,x0.z,x0.w,x1.x,x1.y,x1.z,x1.w};
    float s = 0.f, q = 0.f;
    #pragma unroll
    for (int u=0;u<8;u++){ s += v[u]; q += v[u]*v[u]; }
    #pragma unroll
    for (int m=1;m<16;m<<=1){ s += __shfl_xor(s,m); q += __shfl_xor(q,m); }
    float mean = s*(1.f/128.f);
    float var  = q*(1.f/128.f) - mean*mean;
    float rs = rsqrtf(var + 1e-5f);
    int c0 = l16*8;
    unsigned int pk[4];
    #pragma unroll
    for (int u=0;u<4;u++){
      float z0 = (v[2*u]  -mean)*rs*lng[c0+2*u]   + lnb[c0+2*u];
      float z1 = (v[2*u+1]-mean)*rs*lng[c0+2*u+1] + lnb[c0+2*u+1];
      pk[u] = packbf(z0,z1);
    }
    ((uint4*)(zw + e*CZ))[l16] = make_uint4(pk[0],pk[1],pk[2],pk[3]);
  } else {
    int blk2 = b - 1536;           // 0..383
    int seg = blk2 / 96;           // 0..3
    int within = blk2 - seg*96;
    int gid = within*256 + t;      // 0..24575
    int side = (gid >= 12288) ? 1 : 0;
    int idx = gid - side*12288;
    int nd = idx >> 4, c = idx & 15;
    const float* w = side ? wr : wl;
    float acc = (seg==0) ? (side ? br[c] : bl[c]) : 0.f;
    const float* nrow = nf + (size_t)nd*CS;
    int kb = seg*96;
    #pragma unroll 4
    for (int k=kb;k<kb+96;k++) acc += nrow[k]*w[k*CG+c];
    atomicAdd((side? nrw : nlw)+idx, acc);
  }
}

// ---------- K1b: S_all[s][c*16+l] = nl[s] . wb   (768 blocks) + nr bf16 pack ----------
__global__ __launch_bounds__(256) void k1b_sprep(
    const float* __restrict__ nlw, const float* __restrict__ nrw,
    const unsigned short* __restrict__ wbP,
    unsigned short* __restrict__ S_all, unsigned short* __restrict__ nrb)
{
  int n = blockIdx.x, t = threadIdx.x;
  float e1[16];
  #pragma unroll
  for (int k=0;k<16;k++) e1[k] = nlw[n*CG + k];
  int c = t>>1, l0 = (t&1)*8;
  float S[8];
  #pragma unroll
  for (int u=0;u<8;u++) S[u]=0.f;
  const unsigned short* wrow = wbP + c*256 + l0;
  #pragma unroll 4
  for (int k=0;k<16;k++){
    uint4 wv = *(const uint4*)(wrow + k*16);
    float wf[8] = { bfl(wv.x), bfh(wv.x), bfl(wv.y), bfh(wv.y),
                    bfl(wv.z), bfh(wv.z), bfl(wv.w), bfh(wv.w) };
    float ev = e1[k];
    #pragma unroll
    for (int u=0;u<8;u++) S[u] += ev*wf[u];
  }
  *(uint4*)(S_all + (size_t)n*2048 + c*16 + l0) = make_uint4(
    packbf(S[0],S[1]), packbf(S[2],S[3]), packbf(S[4],S[5]), packbf(S[6],S[7]));
  if (t < 8){
    *(unsigned int*)(nrb + n*CG + 2*t) = packbf(nrw[n*CG + 2*t], nrw[n*CG + 2*t + 1]);
  }
}

// ---------- K2 (MFMA, lean — R8-proven shape): bias[n][h][i][j] per (node, 4-i chunk) ----------
// All GEMM operands except rbf/X live in registers (loaded straight from global in
// MFMA fragment shape). LDS only: rbfb (4.5K) + Xb (8.5K) + t3s/dsm/srcs (~1.2K).
__global__ __launch_bounds__(256,4) void k2_bias(
    const long long* __restrict__ eidx, const float* __restrict__ trans,
    const unsigned short* __restrict__ S_all, const unsigned short* __restrict__ nrb,
    const unsigned short* __restrict__ wdTg, const unsigned short* __restrict__ wtTg,
    const float* __restrict__ bg, const float* __restrict__ bd,
    float* __restrict__ biasw)
{
  int n = blockIdx.x >> 3, chunk = blockIdx.x & 7;
  int i0 = chunk*4;
  int t = threadIdx.x;
  int wave = t>>6, lane = t&63, q = lane>>4, l15 = lane&15;

  __shared__ __align__(16) unsigned short rbfb[32*72];   // 4.5 KB  [j][r]
  __shared__ __align__(16) unsigned short Xb  [32*136];  // 8.5 KB  [j][c]
  __shared__ __align__(16) float t3s[32][4];
  __shared__ __align__(16) float dsm[4][32];
  __shared__ int srcs[32];

  f32x4 zero4 = {0.f,0.f,0.f,0.f};
  uint4 uz = make_uint4(0,0,0,0);

  // ph0: srcs
  if (t < 32) srcs[t] = (int)eidx[(size_t)n*KKN + t];
  __syncthreads();
  // ph1: t3s gather + per-lane invariant fragments
  if (t < 32){ int s = srcs[t];
    t3s[t][0]=trans[s*3]; t3s[t][1]=trans[s*3+1]; t3s[t][2]=trans[s*3+2]; }
  // wd A-frags (regs, whole kernel): rows c = wave*32+mt*16+l15, k = ks*32+q*8
  uint4 wdf[2][2];
  #pragma unroll
  for (int mt=0;mt<2;mt++){
    #pragma unroll
    for (int ks=0;ks<2;ks++)
      wdf[mt][ks] = *(const uint4*)(wdTg + (wave*32+mt*16+l15)*72 + ks*32 + q*8);
  }
  // wt A-frags (regs): rows h = l15&3 (rows >=4 discarded), k = ks*32+q*8
  uint4 wtf[4];
  #pragma unroll
  for (int ks=0;ks<4;ks++)
    wtf[ks] = *(const uint4*)(wtTg + (l15&3)*136 + ks*32 + q*8);
  // e2 B-frags (regs, i-invariant): rows j = nt*16+l15, k = l (q<2 real, q>=2 zero)
  uint4 bE[2];
  #pragma unroll
  for (int nt=0;nt<2;nt++){
    int jn = srcs[nt*16 + l15];
    bE[nt] = (q < 2) ? *(const uint4*)(nrb + jn*CG + q*8) : uz;
  }
  __syncthreads();
  // ph2: distances
  if (t < 128){
    int ii=t>>5, j=t&31;
    float dx=t3s[i0+ii][0]-t3s[j][0]+1e-8f;
    float dy=t3s[i0+ii][1]-t3s[j][1]+1e-8f;
    float dz=t3s[i0+ii][2]-t3s[j][2]+1e-8f;
    dsm[ii][j]=sqrtf(dx*dx+dy*dy+dz*dz);
  }
  __syncthreads();

  int jr = t>>3, sl = t&7;
  int c0base = wave*32 + q*4;

  #pragma unroll 1
  for (int ii=0; ii<4; ii++){
    // aS frags for this i (source node s_i, wave-uniform)
    int s_i = srcs[i0+ii];
    uint4 aS[2];
    #pragma unroll
    for (int mt=0;mt<2;mt++)
      aS[mt] = (q < 2) ? *(const uint4*)(S_all + (size_t)s_i*2048 + (wave*32+mt*16+l15)*16 + q*8) : uz;
    // dense rbf fill (out-of-range terms underflow to exact 0)
    {
      float dI = dsm[ii][jr]*RBF_INVSIG;
      #pragma unroll
      for (int u=0;u<9;u++){
        int r = sl*9+u;
        float x = fmaf((float)r, -RBF_SI, dI);
        rbfb[jr*72+r] = f2bf(__expf(-x*x));
      }
    }
    __syncthreads();

    f32x4 ga[2][2], da[2][2];
    #pragma unroll
    for(int a=0;a<2;a++){
      #pragma unroll
      for(int b2=0;b2<2;b2++){ ga[a][b2]=zero4; da[a][b2]=zero4; }
    }
    #pragma unroll
    for(int mt=0;mt<2;mt++){
      #pragma unroll
      for(int nt=0;nt<2;nt++)
        ga[mt][nt] = __builtin_amdgcn_mfma_f32_16x16x32_bf16(
          *(const bf16x8*)&aS[mt], *(const bf16x8*)&bE[nt], ga[mt][nt], 0,0,0);
    }
    #pragma unroll
    for(int ks=0;ks<2;ks++){
      bf16x8 bR[2];
      #pragma unroll
      for(int nt=0;nt<2;nt++) bR[nt] = *(const bf16x8*)&rbfb[(nt*16+l15)*72 + ks*32 + q*8];
      #pragma unroll
      for(int mt=0;mt<2;mt++){
        #pragma unroll
        for(int nt=0;nt<2;nt++)
          da[mt][nt] = __builtin_amdgcn_mfma_f32_16x16x32_bf16(
            *(const bf16x8*)&wdf[mt][ks], bR[nt], da[mt][nt], 0,0,0);
      }
    }
    // epilogue: X[j][c] = sigmoid(ga+bg)*(da+bd), bf16
    #pragma unroll
    for(int mt=0;mt<2;mt++){
      int c0 = c0base + mt*16;
      float4 bgv = *(const float4*)(bg + c0);
      float4 bdv = *(const float4*)(bd + c0);
      #pragma unroll
      for(int nt=0;nt<2;nt++){
        float x0 = sigm(ga[mt][nt][0]+bgv.x)*(da[mt][nt][0]+bdv.x);
        float x1 = sigm(ga[mt][nt][1]+bgv.y)*(da[mt][nt][1]+bdv.y);
        float x2 = sigm(ga[mt][nt][2]+bgv.z)*(da[mt][nt][2]+bdv.z);
        float x3 = sigm(ga[mt][nt][3]+bgv.w)*(da[mt][nt][3]+bdv.w);
        *(uint2*)&Xb[(nt*16+l15)*136 + c0] = make_uint2(packbf(x0,x1), packbf(x2,x3));
      }
    }
    __syncthreads();

    // final: biasT[h][j] = wt[h][:] . X[j][:], waves 0,1 (j-halves)
    if (wave < 2){
      f32x4 bacc = {0.f,0.f,0.f,0.f};
      #pragma unroll
      for(int ks=0;ks<4;ks++){
        bf16x8 bX = *(const bf16x8*)&Xb[(wave*16+l15)*136 + ks*32 + q*8];
        bacc = __builtin_amdgcn_mfma_f32_16x16x32_bf16(*(const bf16x8*)&wtf[ks], bX, bacc, 0,0,0);
      }
      if (q==0){   // rows h=0..3 in quad-0 regs; layout [n][h][i][j]
        int j = wave*16 + l15;
        float* base = biasw + (((size_t)n*4)*32 + (i0+ii))*32 + j;
        base[0] = bacc[0]; base[1024] = bacc[1]; base[2048] = bacc[2]; base[3072] = bacc[3];
      }
    }
  }
}

// ---------- K3: per-node QKV+og (MFMA) + attention + out-proj (MFMA) ----------
__global__ __launch_bounds__(256,3) void k3_attn(
    const unsigned short* __restrict__ zw, const float* __restrict__ biasw,
    const unsigned short* __restrict__ wqkvogT, const unsigned short* __restrict__ woutT,
    const float* __restrict__ bq, const float* __restrict__ bkv, const float* __restrict__ bog,
    const float* __restrict__ bout, float* __restrict__ out)
{
  int n = blockIdx.x, t = threadIdx.x;
  int w = t>>6, lane = t&63, q = lane>>4, l15 = lane&15;
  int i3 = lane>>1, jh = lane&1;

  __shared__ __align__(16) char smem[49152];
  uint4* wdst = (uint4*)(smem + 32768);
  unsigned short* wtS = (unsigned short*)(smem + 32768);
  f32x4 zero4 = {0.f,0.f,0.f,0.f};

  bf16x8 zfr[2][4];
  #pragma unroll
  for (int nt=0;nt<2;nt++){
    const unsigned short* zr = zw + ((size_t)n*32 + nt*16 + l15)*128;
    #pragma unroll
    for (int ks=0;ks<4;ks++) zfr[nt][ks] = *(const bf16x8*)(zr + ks*32 + q*8);
  }
  f32x4 br4[4];
  {
    const f32x4* bsrc = (const f32x4*)(biasw + (((size_t)n*4 + w)*32 + i3)*32 + jh*16);
    #pragma unroll
    for (int u=0;u<4;u++) br4[u] = bsrc[u];
  }
  const float* bseg = (w==0)? bq : (w==1)? bkv : (w==2)? (bkv+128) : bog;

  const uint4* wsrc = (const uint4*)wqkvogT;
  int sb = w*2048, db = w*256;
  uint4 sreg[4];
  #pragma unroll
  for (int u=0;u<4;u++) sreg[u] = wsrc[sb + u*64 + lane];
  const unsigned short* arow = wtS + w*2048 + l15*128;
  for (int r=0;r<8;r++){
    #pragma unroll
    for (int u=0;u<4;u++) wdst[db + u*64 + lane] = sreg[u];
    if (r<7){
      #pragma unroll
      for (int u=0;u<4;u++) sreg[u] = wsrc[sb + (r+1)*256 + u*64 + lane];
    }
    float4 bv = *(const float4*)(bseg + r*16 + q*4);
    f32x4 acc0 = zero4, acc1 = zero4;
    int cg = w*128 + r*16 + l15;
    #pragma unroll
    for (int ks=0;ks<4;ks++){
      bf16x8 af = *(const bf16x8*)(arow + (((ks*4+q) + cg)&15)*8);
      acc0 = __builtin_amdgcn_mfma_f32_16x16x32_bf16(af, zfr[0][ks], acc0, 0,0,0);
      acc1 = __builtin_amdgcn_mfma_f32_16x16x32_bf16(af, zfr[1][ks], acc1, 0,0,0);
    }
    #pragma unroll
    for (int nt=0;nt<2;nt++){
      f32x4 a = nt? acc1 : acc0;
      float v0,v1,v2,v3;
      if (w==3){ v0=sigm(a[0]+bv.x); v1=sigm(a[1]+bv.y); v2=sigm(a[2]+bv.z); v3=sigm(a[3]+bv.w); }
      else     { v0=a[0]+bv.x; v1=a[1]+bv.y; v2=a[2]+bv.z; v3=a[3]+bv.w; }
      int i = nt*16 + l15;
      int blk = ((r*2 + (q>>1)) + i) & 15;
      *(uint2*)(smem + w*8192 + i*256 + blk*16 + (q&1)*8) = make_uint2(packbf(v0,v1), packbf(v2,v3));
    }
  }
  __syncthreads();

  float sc[16];
  {
    float qreg[32];
    #pragma unroll
    for (int dq=0;dq<4;dq++){
      uint4 qa = *(const uint4*)(smem + i3*256 + (((w*4+dq) + i3)&15)*16);
      unsigned int qu[4] = {qa.x,qa.y,qa.z,qa.w};
      #pragma unroll
      for (int u2=0;u2<4;u2++){ qreg[dq*8+2*u2]=bfl(qu[u2]); qreg[dq*8+2*u2+1]=bfh(qu[u2]); }
    }
    int j0 = jh*16;
    #pragma unroll
    for (int jj=0;jj<16;jj++){
      int j = j0+jj;
      float s = 0.f;
      #pragma unroll
      for (int dq=0;dq<4;dq++){
        uint4 ka = *(const uint4*)(smem + 8192 + j*256 + (((w*4+dq) + j)&15)*16);
        unsigned int ku[4] = {ka.x,ka.y,ka.z,ka.w};
        #pragma unroll
        for (int u2=0;u2<4;u2++)
          s += qreg[dq*8+2*u2]*bfl(ku[u2]) + qreg[dq*8+2*u2+1]*bfh(ku[u2]);
      }
      sc[jj] = s*0.17677669529663687f + br4[jj>>2][jj&3];
    }
  }
  {
    float mx = sc[0];
    #pragma unroll
    for (int jj=1;jj<16;jj++) mx = fmaxf(mx, sc[jj]);
    mx = fmaxf(mx, __shfl_xor(mx,1));
    float sum = 0.f;
    #pragma unroll
    for (int jj=0;jj<16;jj++){ sc[jj] = __expf(sc[jj]-mx); sum += sc[jj]; }
    sum += __shfl_xor(sum,1);
    float inv = 1.0f/sum;
    #pragma unroll
    for (int jj=0;jj<16;jj++) sc[jj] *= inv;
  }
  __syncthreads();
  {
    int dbase = w*32 + jh*16;
    int db8 = dbase >> 3;
    float o16[16];
    #pragma unroll
    for (int u=0;u<16;u++) o16[u]=0.f;
    #pragma unroll
    for (int j=0;j<32;j++){
      float pj = __shfl(sc[j & 15], (lane & 62) | (j >> 4));
      uint4 va0 = *(const uint4*)(smem + 16384 + j*256 + (((db8+0) + j)&15)*16);
      uint4 va1 = *(const uint4*)(smem + 16384 + j*256 + (((db8+1) + j)&15)*16);
      unsigned int vu[8] = {va0.x,va0.y,va0.z,va0.w,va1.x,va1.y,va1.z,va1.w};
      #pragma unroll
      for (int u2=0;u2<8;u2++){ o16[2*u2] += pj*bfl(vu[u2]); o16[2*u2+1] += pj*bfh(vu[u2]); }
    }
    uint4 ga0 = *(const uint4*)(smem + 24576 + i3*256 + (((db8+0) + i3)&15)*16);
    uint4 ga1 = *(const uint4*)(smem + 24576 + i3*256 + (((db8+1) + i3)&15)*16);
    unsigned int gu[8] = {ga0.x,ga0.y,ga0.z,ga0.w,ga1.x,ga1.y,ga1.z,ga1.w};
    #pragma unroll
    for (int u2=0;u2<8;u2++){
      float y0 = o16[2*u2]  *bfl(gu[u2]);
      float y1 = o16[2*u2+1]*bfh(gu[u2]);
      int c = dbase + 2*u2;
      *(unsigned int*)(smem + i3*256 + (((c>>3) + i3)&15)*16 + (c&7)*2) = packbf(y0,y1);
    }
  }
  __syncthreads();

  bf16x8 yfr[2][4];
  #pragma unroll
  for (int mt=0;mt<2;mt++){
    int row = mt*16 + l15;
    #pragma unroll
    for (int ks=0;ks<4;ks++)
      yfr[mt][ks] = *(const bf16x8*)(smem + row*256 + (((ks*4+q) + row)&15)*16);
  }
  const uint4* osrc = (const uint4*)woutT;
  #pragma unroll
  for (int r2=0;r2<2;r2++){
    int c0 = (r2*4 + w)*16;
    #pragma unroll
    for (int u=0;u<4;u++) wdst[db + u*64 + lane] = osrc[c0*16 + u*64 + lane];
    int cg2 = c0 + l15;
    const unsigned short* brow = wtS + w*2048 + l15*128;
    f32x4 oa0 = zero4, oa1 = zero4;
    #pragma unroll
    for (int ks=0;ks<4;ks++){
      bf16x8 bf = *(const bf16x8*)(brow + (((ks*4+q) + cg2)&15)*8);
      oa0 = __builtin_amdgcn_mfma_f32_16x16x32_bf16(yfr[0][ks], bf, oa0, 0,0,0);
      oa1 = __builtin_amdgcn_mfma_f32_16x16x32_bf16(yfr[1][ks], bf, oa1, 0,0,0);
    }
    float bov = bout[cg2];
    #pragma unroll
    for (int mt=0;mt<2;mt++){
      f32x4 oa = mt? oa1 : oa0;
      #pragma unroll
      for (int rg=0; rg<4; rg++){
        int i = mt*16 + q*4 + rg;
        out[((size_t)n*32 + i)*128 + cg2] = oa[rg] + bov;
      }
    }
  }
}

// ---------- launch ----------
extern "C" void kernel_launch(void* const* d_in, const int* in_sizes, int n_in,
                              void* d_out, int out_size, void* d_ws, size_t ws_size,
                              hipStream_t stream)
{
  const float* nf  = (const float*)d_in[0];
  const float* tr  = (const float*)d_in[1];
  const float* ef  = (const float*)d_in[2];
  const long long* ei = (const long long*)d_in[3];
  const float* wl  = (const float*)d_in[4];  const float* bl  = (const float*)d_in[5];
  const float* wr  = (const float*)d_in[6];  const float* br  = (const float*)d_in[7];
  const float* wbg = (const float*)d_in[8];  const float* bbg = (const float*)d_in[9];
  const float* wdi = (const float*)d_in[10]; const float* bdi = (const float*)d_in[11];
  const float* wtb = (const float*)d_in[12];
  const float* lng = (const float*)d_in[13]; const float* lnb = (const float*)d_in[14];
  const float* wq  = (const float*)d_in[15]; const float* bq  = (const float*)d_in[16];
  const float* wkv = (const float*)d_in[17]; const float* bkv = (const float*)d_in[18];
  const float* wo  = (const float*)d_in[19]; const float* bo  = (const float*)d_in[20];
  const float* wog = (const float*)d_in[21]; const float* bog = (const float*)d_in[22];
  float* outp = (float*)d_out;
  float* ws = (float*)d_ws;
  // ws layout (floats). zw = E*CZ bf16 = 1,572,864 floats.
  float* nlw = ws;                                            // [0, 12288)
  float* nrw = ws + 12288;                                    // [12288, 24576)
  float* biasw = ws + 24576;                                  // [24576, 3170304)  [n][h][i][j]
  unsigned short* zw      = (unsigned short*)(ws + 3170304);  // [3170304, 4743168)
  unsigned short* wqkvogT = (unsigned short*)(ws + 4743168);  // 32768 floats
  unsigned short* woutT   = (unsigned short*)(ws + 4775936);  // 8192 floats
  unsigned short* wdTg    = (unsigned short*)(ws + 4784128);  // 4608 floats
  unsigned short* wtTg    = (unsigned short*)(ws + 4788736);  // 1088 floats
  unsigned short* wbPg    = (unsigned short*)(ws + 4789824);  // 16384 floats
  unsigned short* S_all   = (unsigned short*)(ws + 4806208);  // 786432 floats
  unsigned short* nrb     = (unsigned short*)(ws + 5592640);  // 6144 floats -> end 5598784

  hipLaunchKernelGGL(k0_prep, dim3(85), dim3(256), 0, stream,
                     wq, wkv, wog, wo, wdi, wtb, wbg, wqkvogT, woutT, wdTg, wtTg, wbPg, nlw);
  hipLaunchKernelGGL(k1_pre, dim3(1920), dim3(256), 0, stream,
                     nf, ef, wl, bl, wr, br, lng, lnb, nlw, nrw, zw);
  hipLaunchKernelGGL(k1b_sprep, dim3(768), dim3(256), 0, stream,
                     nlw, nrw, wbPg, S_all, nrb);
  hipLaunchKernelGGL(k2_bias, dim3(6144), dim3(256), 0, stream,
                     ei, tr, S_all, nrb, wdTg, wtTg, bbg, bdi, biasw);
  hipLaunchKernelGGL(k3_attn, dim3(768), dim3(256), 0, stream,
                     zw, biasw, wqkvogT, woutT, bq, bkv, bog, bo, outp);
}